// Round 2
// baseline (414.054 us; speedup 1.0000x reference)
//
#include <hip/hip_runtime.h>
#include <hip/hip_bf16.h>

// DisenHAN fused kernel for MI355X (gfx950).
// One 256-thread workgroup per (batch, branch). All intermediates live in LDS.
// T=1 collapses the hete-attention: beta==1, wp==1 (softmax over a singleton
// axis), so routing = 3x { per-facet logits -> softmax over 16 neighbors ->
// aggregate -> htmp = hid + z }, and the 16 s-slots are independent.
// All float tensors are fp32 (reference uses jnp.float32 throughout).

#define NTH 256

__global__ __launch_bounds__(256, 2)
void disenhan_fused(const float* __restrict__ user_table,
                    const float* __restrict__ item_table,
                    const float* __restrict__ W0u,
                    const float* __restrict__ W0i,
                    const float* __restrict__ W1u,
                    const float* __restrict__ W1i,
                    const int* __restrict__ uidx0, const int* __restrict__ uidx1,
                    const int* __restrict__ uidx2,
                    const int* __restrict__ iidx0, const int* __restrict__ iidx1,
                    const int* __restrict__ iidx2,
                    float* __restrict__ out, int B)
{
    constexpr float SCALE = 0.35355339059327373f;  // 1/sqrt(8)
    const int b = blockIdx.x;
    const int branch = blockIdx.y;
    const int tid = threadIdx.x;
    if (b >= B) return;

    // Branch-dependent bindings (see reference _branch calls):
    // user: e0,e2 from user_table; e1 from item_table; W1c=Wpre1_item, W1n=Wpre1_user, W0n=Wpre0_item
    // item: mirrored.
    const float *tab0, *tab1, *W1c, *W1n, *W0n;
    const int *idx0, *idx1, *idx2;
    if (branch == 0) { tab0 = user_table; tab1 = item_table;
                       idx0 = uidx0; idx1 = uidx1; idx2 = uidx2;
                       W1c = W1i; W1n = W1u; W0n = W0i; }
    else             { tab0 = item_table; tab1 = user_table;
                       idx0 = iidx0; idx1 = iidx1; idx2 = iidx2;
                       W1c = W1u; W1n = W1i; W0n = W0u; }

    __shared__ float sW[64 * 64];    // current weight, row-major W[d][j]
    __shared__ float sX[64 * 68];    // gathered input rows, pitch 68 (float4-aligned, bank-spread)
    __shared__ float sN[64 * 68];    // nh chunk, pitch 68
    __shared__ float sC[16 * 64];    // c = hid (layer-1 center pre-encode)
    __shared__ float sH[16 * 64];    // htmp / h1
    __shared__ float sL[512];        // logits for 4-s chunk: [si][n][k]
    __shared__ float sV0[64];        // layer-0 c (= e0)
    __shared__ float sH0[64];        // layer-0 htmp
    __shared__ float sL0[128];       // layer-0 logits [n][k]

    // ---------------- load W1c + gather e1 rows (vectorized float4) ----------------
    for (int i = tid; i < 1024; i += NTH)
        *(float4*)&sW[i * 4] = *(const float4*)&W1c[i * 4];
    for (int i = tid; i < 16 * 16; i += NTH) {
        int s = i >> 4, c4 = i & 15;
        int g = idx1[b * 16 + s];
        *(float4*)&sX[s * 68 + c4 * 4] = *(const float4*)&tab1[(long)g * 64 + c4 * 4];
    }
    __syncthreads();

    // ---------------- hid = e1 @ W1c -> sC, sH ----------------
    {
        int r = tid >> 4;
        int j0 = (tid & 15) * 4;
        float4 acc = {0.f, 0.f, 0.f, 0.f};
        for (int d = 0; d < 64; ++d) {
            float xv = sX[r * 68 + d];
            const float4 wv = *(const float4*)&sW[d * 64 + j0];
            acc.x = fmaf(xv, wv.x, acc.x);
            acc.y = fmaf(xv, wv.y, acc.y);
            acc.z = fmaf(xv, wv.z, acc.z);
            acc.w = fmaf(xv, wv.w, acc.w);
        }
        *(float4*)&sC[r * 64 + j0] = acc;
        *(float4*)&sH[r * 64 + j0] = acc;
    }
    __syncthreads();

    // ---------------- load W1n ----------------
    for (int i = tid; i < 1024; i += NTH)
        *(float4*)&sW[i * 4] = *(const float4*)&W1n[i * 4];

    // ---------------- layer-1: process s in chunks of 4 ----------------
    for (int sc = 0; sc < 4; ++sc) {
        __syncthreads();  // sW visible (first chunk) / prior readers of sX done
        // gather 64 e2 rows for s in [sc*4, sc*4+4)
        for (int i = tid; i < 64 * 16; i += NTH) {
            int r = i >> 4, c4 = i & 15;
            int g = idx2[b * 256 + sc * 64 + r];
            *(float4*)&sX[r * 68 + c4 * 4] = *(const float4*)&tab0[(long)g * 64 + c4 * 4];
        }
        __syncthreads();
        // nh = e2 @ W1n -> sN  (4 rows x 4 cols per thread)
        {
            int rg = tid >> 4;             // row group: rows rg*4 .. rg*4+3
            int j0 = (tid & 15) * 4;
            const float* xb = &sX[(rg * 4) * 68];
            float4 a0 = {0,0,0,0}, a1 = {0,0,0,0}, a2 = {0,0,0,0}, a3 = {0,0,0,0};
            for (int d = 0; d < 64; ++d) {
                const float4 wv = *(const float4*)&sW[d * 64 + j0];
                const float x0 = xb[d];
                const float x1 = xb[68 + d];
                const float x2 = xb[136 + d];
                const float x3 = xb[204 + d];
                a0.x = fmaf(x0, wv.x, a0.x); a0.y = fmaf(x0, wv.y, a0.y);
                a0.z = fmaf(x0, wv.z, a0.z); a0.w = fmaf(x0, wv.w, a0.w);
                a1.x = fmaf(x1, wv.x, a1.x); a1.y = fmaf(x1, wv.y, a1.y);
                a1.z = fmaf(x1, wv.z, a1.z); a1.w = fmaf(x1, wv.w, a1.w);
                a2.x = fmaf(x2, wv.x, a2.x); a2.y = fmaf(x2, wv.y, a2.y);
                a2.z = fmaf(x2, wv.z, a2.z); a2.w = fmaf(x2, wv.w, a2.w);
                a3.x = fmaf(x3, wv.x, a3.x); a3.y = fmaf(x3, wv.y, a3.y);
                a3.z = fmaf(x3, wv.z, a3.z); a3.w = fmaf(x3, wv.w, a3.w);
            }
            *(float4*)&sN[(rg * 4 + 0) * 68 + j0] = a0;
            *(float4*)&sN[(rg * 4 + 1) * 68 + j0] = a1;
            *(float4*)&sN[(rg * 4 + 2) * 68 + j0] = a2;
            *(float4*)&sN[(rg * 4 + 3) * 68 + j0] = a3;
        }
        __syncthreads();
        // routing: 3 iterations over this chunk's 4 s-slots
        for (int it = 0; it < 3; ++it) {
            // logits e[si][n][k] = scale * <htmp[s][k,:], nh[s][n][k,:]>
            for (int i = tid; i < 512; i += NTH) {
                int r = i >> 3;              // 0..63 : si = r>>4, n = r&15
                int k = i & 7;
                int s = sc * 4 + (r >> 4);
                float dot = 0.f;
#pragma unroll
                for (int d = 0; d < 8; ++d)
                    dot += sH[s * 64 + k * 8 + d] * sN[r * 68 + k * 8 + d];
                sL[i] = dot * SCALE;
            }
            __syncthreads();
            // softmax over n for each (si,k)
            if (tid < 32) {
                int si = tid >> 3, k = tid & 7;
                float m = -1e30f;
#pragma unroll
                for (int n = 0; n < 16; ++n) m = fmaxf(m, sL[(si * 16 + n) * 8 + k]);
                float ssum = 0.f;
#pragma unroll
                for (int n = 0; n < 16; ++n) {
                    float e = __expf(sL[(si * 16 + n) * 8 + k] - m);
                    sL[(si * 16 + n) * 8 + k] = e;
                    ssum += e;
                }
                float inv = 1.f / ssum;
#pragma unroll
                for (int n = 0; n < 16; ++n) sL[(si * 16 + n) * 8 + k] *= inv;
            }
            __syncthreads();
            // htmp[s][j] = c[s][j] + sum_n a[si][n][k] * nh[si*16+n][j]; relu on last iter
            {
                int si = tid >> 6, j = tid & 63, k = j >> 3;
                int s = sc * 4 + si;
                float z = 0.f;
#pragma unroll
                for (int n = 0; n < 16; ++n)
                    z += sL[(si * 16 + n) * 8 + k] * sN[(si * 16 + n) * 68 + j];
                float v = sC[s * 64 + j] + z;
                if (it == 2) v = fmaxf(v, 0.f);  // h1 = relu(htmp)
                sH[s * 64 + j] = v;
            }
            __syncthreads();
        }
    }

    // ---------------- layer-0 ----------------
    for (int i = tid; i < 1024; i += NTH)
        *(float4*)&sW[i * 4] = *(const float4*)&W0n[i * 4];
    if (tid < 64) {
        int g = idx0[b];
        float v = tab0[(long)g * 64 + tid];
        sV0[tid] = v;
        sH0[tid] = v;
    }
    __syncthreads();
    // nh0 = h1 @ W0n -> sN rows 0..15
    {
        int r = tid >> 4;
        int j0 = (tid & 15) * 4;
        float4 acc = {0.f, 0.f, 0.f, 0.f};
        for (int d = 0; d < 64; ++d) {
            float xv = sH[r * 64 + d];
            const float4 wv = *(const float4*)&sW[d * 64 + j0];
            acc.x = fmaf(xv, wv.x, acc.x);
            acc.y = fmaf(xv, wv.y, acc.y);
            acc.z = fmaf(xv, wv.z, acc.z);
            acc.w = fmaf(xv, wv.w, acc.w);
        }
        *(float4*)&sN[r * 68 + j0] = acc;
    }
    __syncthreads();
    for (int it = 0; it < 3; ++it) {
        if (tid < 128) {
            int n = tid >> 3, k = tid & 7;
            float dot = 0.f;
#pragma unroll
            for (int d = 0; d < 8; ++d)
                dot += sH0[k * 8 + d] * sN[n * 68 + k * 8 + d];
            sL0[n * 8 + k] = dot * SCALE;
        }
        __syncthreads();
        if (tid < 8) {
            int k = tid;
            float m = -1e30f;
#pragma unroll
            for (int n = 0; n < 16; ++n) m = fmaxf(m, sL0[n * 8 + k]);
            float ssum = 0.f;
#pragma unroll
            for (int n = 0; n < 16; ++n) {
                float e = __expf(sL0[n * 8 + k] - m);
                sL0[n * 8 + k] = e;
                ssum += e;
            }
            float inv = 1.f / ssum;
#pragma unroll
            for (int n = 0; n < 16; ++n) sL0[n * 8 + k] *= inv;
        }
        __syncthreads();
        if (tid < 64) {
            int j = tid, k = j >> 3;
            float z = 0.f;
#pragma unroll
            for (int n = 0; n < 16; ++n)
                z += sL0[n * 8 + k] * sN[n * 68 + j];
            sH0[j] = sV0[j] + z;  // no relu in layer-0
        }
        __syncthreads();
    }
    if (tid < 64)
        out[((long)branch * B + b) * 64 + tid] = sH0[tid];
}

extern "C" void kernel_launch(void* const* d_in, const int* in_sizes, int n_in,
                              void* d_out, int out_size, void* d_ws, size_t ws_size,
                              hipStream_t stream) {
    const float* user_table = (const float*)d_in[0];
    const float* item_table = (const float*)d_in[1];
    const float* W0u = (const float*)d_in[2];
    const float* W0i = (const float*)d_in[3];
    const float* W1u = (const float*)d_in[4];
    const float* W1i = (const float*)d_in[5];
    const int* uidx0 = (const int*)d_in[6];
    const int* uidx1 = (const int*)d_in[7];
    const int* uidx2 = (const int*)d_in[8];
    const int* iidx0 = (const int*)d_in[9];
    const int* iidx1 = (const int*)d_in[10];
    const int* iidx2 = (const int*)d_in[11];
    float* out = (float*)d_out;

    const int B = in_sizes[6];  // 2048
    dim3 grid(B, 2), block(NTH);
    hipLaunchKernelGGL(disenhan_fused, grid, block, 0, stream,
                       user_table, item_table, W0u, W0i, W1u, W1i,
                       uidx0, uidx1, uidx2, iidx0, iidx1, iidx2, out, B);
}

// Round 4
// 208.985 us; speedup vs baseline: 1.9813x; 1.9813x over previous
//
#include <hip/hip_runtime.h>
#include <hip/hip_bf16.h>

// DisenHAN fused, MFMA split-bf16 edition (gfx950).
// One 256-thread block per (batch, branch); wave w owns s-slots 4w..4w+3
// end-to-end. All matmuls are mfma_f32_16x16x32_bf16 with 3-pass split-bf16
// (hi/lo) emulation for ~fp32 accuracy: A_hi*W_hi + A_lo*W_hi + A_hi*W_lo.
// A-fragments come from global gathers in registers; W fragments resident in
// 64 VGPRs (hi+lo). Routing softmax is register+shuffle. One __syncthreads.
// T=1 collapses hete-attention: beta==1, wp==1 forever.

#define NTH 256

typedef __attribute__((ext_vector_type(8))) short bf16x8;   // 8 bf16 (4 VGPRs)
typedef __attribute__((ext_vector_type(4))) float floatx4;

__device__ __forceinline__ short f2bf(float f) {            // RNE fp32->bf16
    unsigned u = __builtin_bit_cast(unsigned, f);
    unsigned r = u + 0x7fffu + ((u >> 16) & 1u);
    return (short)(r >> 16);
}
__device__ __forceinline__ float bf2f_s(short h) {
    return __builtin_bit_cast(float, (unsigned)((unsigned short)h) << 16);
}

// split x -> hi + lo bf16 (hi=RNE(x), lo=RNE(x-hi)); ~16 mantissa bits total
__device__ __forceinline__ void split_pack8(float4 a, float4 b, bf16x8& hi, bf16x8& lo) {
    float v[8] = {a.x, a.y, a.z, a.w, b.x, b.y, b.z, b.w};
#pragma unroll
    for (int i = 0; i < 8; ++i) {
        short h = f2bf(v[i]);
        hi[i] = h;
        lo[i] = f2bf(v[i] - bf2f_s(h));
    }
}

__device__ __forceinline__ floatx4 mfma3(bf16x8 Ah, bf16x8 Al, bf16x8 Wh, bf16x8 Wl,
                                         floatx4 acc) {
    acc = __builtin_amdgcn_mfma_f32_16x16x32_bf16(Ah, Wh, acc, 0, 0, 0);
    acc = __builtin_amdgcn_mfma_f32_16x16x32_bf16(Al, Wh, acc, 0, 0, 0);
    acc = __builtin_amdgcn_mfma_f32_16x16x32_bf16(Ah, Wl, acc, 0, 0, 0);
    return acc;
}

__global__ __launch_bounds__(256, 3)
void disenhan_mfma(const float* __restrict__ user_table,
                   const float* __restrict__ item_table,
                   const float* __restrict__ W0u, const float* __restrict__ W0i,
                   const float* __restrict__ W1u, const float* __restrict__ W1i,
                   const int* __restrict__ uidx0, const int* __restrict__ uidx1,
                   const int* __restrict__ uidx2,
                   const int* __restrict__ iidx0, const int* __restrict__ iidx1,
                   const int* __restrict__ iidx2,
                   float* __restrict__ out, int B)
{
    constexpr float SCALE = 0.35355339059327373f;  // 1/sqrt(8)
    const int b = blockIdx.x, branch = blockIdx.y;
    const int tid = threadIdx.x;
    const int wv = tid >> 6, lane = tid & 63;
    const int quad = lane >> 4;   // MFMA k-block selector
    const int m16  = lane & 15;   // MFMA row (A) / col (B,D) selector

    const float *tab0, *tab1, *W1c, *W1n, *W0n;
    const int *idx0, *idx1, *idx2;
    if (branch == 0) { tab0 = user_table; tab1 = item_table;
                       idx0 = uidx0; idx1 = uidx1; idx2 = uidx2;
                       W1c = W1i; W1n = W1u; W0n = W0i; }
    else             { tab0 = item_table; tab1 = user_table;
                       idx0 = iidx0; idx1 = iidx1; idx2 = iidx2;
                       W1c = W1u; W1n = W1i; W0n = W0u; }

    __shared__ float sN[4][16 * 68];  // per-wave nh tile (fp32, pitch 68)
    __shared__ float sC[16 * 68];     // hid (= c), pitch 68
    __shared__ float sH[16 * 68];     // htmp / h1, pitch 68
    __shared__ float sA[4][16 * 9];   // per-wave attention weights [n][k], pitch 9
    __shared__ float sE0[64];         // layer-0 center (e0)
    __shared__ float sH0[68];         // layer-0 htmp

    // e0 prefetch (consumed by wave 0 at the end; loaded by all, uniform)
    const float v0 = tab0[(long)idx0[b] * 64 + lane];

    // ---- B-fragment loader: wf[nt][ks][j] = W[ks*32+quad*8+j][nt*16+m16] ----
    bf16x8 wfh[4][2], wfl[4][2];
    auto load_wfrag = [&](const float* __restrict__ W) {
#pragma unroll
        for (int nt = 0; nt < 4; ++nt)
#pragma unroll
            for (int ks = 0; ks < 2; ++ks) {
                const float* wp = &W[(ks * 32 + quad * 8) * 64 + nt * 16 + m16];
                bf16x8 fh, fl;
#pragma unroll
                for (int j = 0; j < 8; ++j) {
                    float x = wp[j * 64];
                    short h = f2bf(x);
                    fh[j] = h;
                    fl[j] = f2bf(x - bf2f_s(h));
                }
                wfh[nt][ks] = fh;
                wfl[nt][ks] = fl;
            }
    };

    // ---- routing: 3 iterations on one s-slot, intra-wave only ----
    auto routing = [&](const float* __restrict__ Nw, float* __restrict__ Hrow,
                       const float* __restrict__ Crow, float* __restrict__ Arow,
                       bool relu_last, float* __restrict__ outp) {
        const int mm = lane >> 3, kk = lane & 7;          // logits: n=mm,mm+8 ; facet kk
        const int r = lane >> 4, j4 = lane & 15, k2 = j4 >> 1;  // update mapping
#pragma unroll
        for (int it = 0; it < 3; ++it) {
            float4 ha = *(const float4*)&Hrow[kk * 8];
            float4 hb = *(const float4*)&Hrow[kk * 8 + 4];
            float4 na = *(const float4*)&Nw[mm * 68 + kk * 8];
            float4 nb = *(const float4*)&Nw[mm * 68 + kk * 8 + 4];
            float4 nc = *(const float4*)&Nw[(mm + 8) * 68 + kk * 8];
            float4 nd = *(const float4*)&Nw[(mm + 8) * 68 + kk * 8 + 4];
            float l0 = (ha.x*na.x + ha.y*na.y + ha.z*na.z + ha.w*na.w +
                        hb.x*nb.x + hb.y*nb.y + hb.z*nb.z + hb.w*nb.w) * SCALE;
            float l1 = (ha.x*nc.x + ha.y*nc.y + ha.z*nc.z + ha.w*nc.w +
                        hb.x*nd.x + hb.y*nd.y + hb.z*nd.z + hb.w*nd.w) * SCALE;
            float mx = fmaxf(l0, l1);
            mx = fmaxf(mx, __shfl_xor(mx, 8));
            mx = fmaxf(mx, __shfl_xor(mx, 16));
            mx = fmaxf(mx, __shfl_xor(mx, 32));
            float e0 = __expf(l0 - mx), e1 = __expf(l1 - mx);
            float sm = e0 + e1;
            sm += __shfl_xor(sm, 8); sm += __shfl_xor(sm, 16); sm += __shfl_xor(sm, 32);
            float inv = 1.0f / sm;
            Arow[mm * 9 + kk] = e0 * inv;
            Arow[(mm + 8) * 9 + kk] = e1 * inv;
            __builtin_amdgcn_wave_barrier();
            // z[j] = sum_n a[n][k(j)] * N[n][j] ; 4 n's per replica r, shuffle-reduced
            float4 z = {0.f, 0.f, 0.f, 0.f};
#pragma unroll
            for (int t = 0; t < 4; ++t) {
                float a = Arow[(4 * r + t) * 9 + k2];
                float4 nv = *(const float4*)&Nw[(4 * r + t) * 68 + j4 * 4];
                z.x = fmaf(a, nv.x, z.x); z.y = fmaf(a, nv.y, z.y);
                z.z = fmaf(a, nv.z, z.z); z.w = fmaf(a, nv.w, z.w);
            }
            z.x += __shfl_xor(z.x, 16); z.y += __shfl_xor(z.y, 16);
            z.z += __shfl_xor(z.z, 16); z.w += __shfl_xor(z.w, 16);
            z.x += __shfl_xor(z.x, 32); z.y += __shfl_xor(z.y, 32);
            z.z += __shfl_xor(z.z, 32); z.w += __shfl_xor(z.w, 32);
            if (r == 0) {
                float4 c = *(const float4*)&Crow[j4 * 4];
                float4 h = {c.x + z.x, c.y + z.y, c.z + z.z, c.w + z.w};
                if (relu_last && it == 2) {
                    h.x = fmaxf(h.x, 0.f); h.y = fmaxf(h.y, 0.f);
                    h.z = fmaxf(h.z, 0.f); h.w = fmaxf(h.w, 0.f);
                }
                *(float4*)&Hrow[j4 * 4] = h;
                if (outp && it == 2) *(float4*)&outp[j4 * 4] = h;
            }
            __builtin_amdgcn_wave_barrier();
        }
    };

    // ================= layer-1 pre-encode: hid = e1 @ W1c =================
    load_wfrag(W1c);
    {
        const long g1 = (long)idx1[b * 16 + m16] * 64;
        const float* p1 = &tab1[g1 + quad * 8];
        bf16x8 A0h, A0l, A1h, A1l;
        split_pack8(*(const float4*)p1, *(const float4*)(p1 + 4), A0h, A0l);
        split_pack8(*(const float4*)(p1 + 32), *(const float4*)(p1 + 36), A1h, A1l);
        floatx4 hacc[4];
#pragma unroll
        for (int nt = 0; nt < 4; ++nt) {
            hacc[nt] = (floatx4){0.f, 0.f, 0.f, 0.f};
            hacc[nt] = mfma3(A0h, A0l, wfh[nt][0], wfl[nt][0], hacc[nt]);
            hacc[nt] = mfma3(A1h, A1l, wfh[nt][1], wfl[nt][1], hacc[nt]);
        }
        // D: row = quad*4+reg, col = nt*16+m16. Wave w keeps its own rows.
        if (quad == wv) {
#pragma unroll
            for (int nt = 0; nt < 4; ++nt)
#pragma unroll
                for (int rg = 0; rg < 4; ++rg) {
                    int row = quad * 4 + rg, col = nt * 16 + m16;
                    float v = hacc[nt][rg];
                    sC[row * 68 + col] = v;
                    sH[row * 68 + col] = v;
                }
        }
    }

    // ================= layer-1 main: 4 s-slots per wave =================
    load_wfrag(W1n);
    int gidx[4];
#pragma unroll
    for (int q = 0; q < 4; ++q)
        gidx[q] = idx2[b * 256 + (wv * 4 + q) * 16 + m16];

    float4 f0, f1, f2, f3;
    {
        const float* p = &tab0[(long)gidx[0] * 64 + quad * 8];
        f0 = *(const float4*)p;        f1 = *(const float4*)(p + 4);
        f2 = *(const float4*)(p + 32); f3 = *(const float4*)(p + 36);
    }
#pragma unroll
    for (int q = 0; q < 4; ++q) {
        const int s = wv * 4 + q;
        bf16x8 A0h, A0l, A1h, A1l;
        split_pack8(f0, f1, A0h, A0l);
        split_pack8(f2, f3, A1h, A1l);
        if (q < 3) {  // prefetch next slot's A rows; consumed next iteration
            const float* p = &tab0[(long)gidx[q + 1] * 64 + quad * 8];
            f0 = *(const float4*)p;        f1 = *(const float4*)(p + 4);
            f2 = *(const float4*)(p + 32); f3 = *(const float4*)(p + 36);
        }
        floatx4 acc[4];
#pragma unroll
        for (int nt = 0; nt < 4; ++nt) {
            acc[nt] = (floatx4){0.f, 0.f, 0.f, 0.f};
            acc[nt] = mfma3(A0h, A0l, wfh[nt][0], wfl[nt][0], acc[nt]);
            acc[nt] = mfma3(A1h, A1l, wfh[nt][1], wfl[nt][1], acc[nt]);
        }
#pragma unroll
        for (int nt = 0; nt < 4; ++nt)
#pragma unroll
            for (int rg = 0; rg < 4; ++rg)
                sN[wv][(quad * 4 + rg) * 68 + nt * 16 + m16] = acc[nt][rg];
        __builtin_amdgcn_wave_barrier();
        routing(sN[wv], &sH[s * 68], &sC[s * 68], sA[wv], true, nullptr);
    }

    // ================= layer-0 =================
    __syncthreads();   // the only block barrier: all h1 rows visible
    if (wv == 0) {
        load_wfrag(W0n);
        sE0[lane] = v0;
        sH0[lane] = v0;
        bf16x8 A0h, A0l, A1h, A1l;
        {
            const float* hp = &sH[m16 * 68];
            split_pack8(*(const float4*)&hp[quad * 8],
                        *(const float4*)&hp[quad * 8 + 4], A0h, A0l);
            split_pack8(*(const float4*)&hp[32 + quad * 8],
                        *(const float4*)&hp[32 + quad * 8 + 4], A1h, A1l);
        }
        floatx4 acc[4];
#pragma unroll
        for (int nt = 0; nt < 4; ++nt) {
            acc[nt] = (floatx4){0.f, 0.f, 0.f, 0.f};
            acc[nt] = mfma3(A0h, A0l, wfh[nt][0], wfl[nt][0], acc[nt]);
            acc[nt] = mfma3(A1h, A1l, wfh[nt][1], wfl[nt][1], acc[nt]);
        }
#pragma unroll
        for (int nt = 0; nt < 4; ++nt)
#pragma unroll
            for (int rg = 0; rg < 4; ++rg)
                sN[0][(quad * 4 + rg) * 68 + nt * 16 + m16] = acc[nt][rg];
        __builtin_amdgcn_wave_barrier();
        routing(sN[0], sH0, sE0, sA[0], false, &out[((long)branch * B + b) * 64]);
    }
}

extern "C" void kernel_launch(void* const* d_in, const int* in_sizes, int n_in,
                              void* d_out, int out_size, void* d_ws, size_t ws_size,
                              hipStream_t stream) {
    const float* user_table = (const float*)d_in[0];
    const float* item_table = (const float*)d_in[1];
    const float* W0u = (const float*)d_in[2];
    const float* W0i = (const float*)d_in[3];
    const float* W1u = (const float*)d_in[4];
    const float* W1i = (const float*)d_in[5];
    const int* uidx0 = (const int*)d_in[6];
    const int* uidx1 = (const int*)d_in[7];
    const int* uidx2 = (const int*)d_in[8];
    const int* iidx0 = (const int*)d_in[9];
    const int* iidx1 = (const int*)d_in[10];
    const int* iidx2 = (const int*)d_in[11];
    float* out = (float*)d_out;

    const int B = in_sizes[6];  // 2048
    dim3 grid(B, 2), block(NTH);
    hipLaunchKernelGGL(disenhan_mfma, grid, block, 0, stream,
                       user_table, item_table, W0u, W0i, W1u, W1i,
                       uidx0, uidx1, uidx2, iidx0, iidx1, iidx2, out, B);
}